// Round 12
// baseline (226.817 us; speedup 1.0000x reference)
//
#include <hip/hip_runtime.h>
#include <hip/hip_bf16.h>

#define N_NODES 50000
#define E_EDGES 800000
#define IN_DIM  256
#define HID     128
#define OUT_DIM 16

#define NBUCK 391    // ceil(50000/128) buckets of 128 nodes (dst>>7)
#define NBLK  128    // blocks for bucket phases A/C
#define P2CAP 4096   // max edges per bucket (mean 2046, sigma ~45)

using frag_ab = __attribute__((ext_vector_type(8))) short;  // 8 bf16
using frag_cd = __attribute__((ext_vector_type(4))) float;  // 4 fp32

static __device__ inline short f2bf(float f) {
    union { float f; unsigned u; } v; v.f = f;
    unsigned r = (v.u + 0x7fffu + ((v.u >> 16) & 1u)) >> 16;
    return (short)r;
}
static __device__ inline float bflo(unsigned u) {
    union { unsigned u; float f; } v; v.u = u << 16; return v.f;
}
static __device__ inline float bfhi(unsigned u) {
    union { unsigned u; float f; } v; v.u = u & 0xffff0000u; return v.f;
}
static __device__ inline unsigned packbf(float a, float b) {
    return (unsigned)(unsigned short)f2bf(a) | ((unsigned)(unsigned short)f2bf(b) << 16);
}

// ================= CSR build: 2-level bucketed counting sort =================

__global__ __launch_bounds__(256) void csr_a(const int4* __restrict__ dst4,
                                             int* __restrict__ cnt_bb) {
    __shared__ int h[NBUCK];
    int t = threadIdx.x;
    for (int i = t; i < NBUCK; i += 256) h[i] = 0;
    __syncthreads();
    for (int i = blockIdx.x * 256 + t; i < E_EDGES / 4; i += NBLK * 256) {
        int4 d = dst4[i];
        atomicAdd(&h[d.x >> 7], 1);
        atomicAdd(&h[d.y >> 7], 1);
        atomicAdd(&h[d.z >> 7], 1);
        atomicAdd(&h[d.w >> 7], 1);
    }
    __syncthreads();
    for (int i = t; i < NBUCK; i += 256) cnt_bb[i * NBLK + blockIdx.x] = h[i];
}

__global__ __launch_bounds__(NBLK) void csr_b1(int* __restrict__ cnt_bb,
                                               int* __restrict__ btot) {
    __shared__ int sm[NBLK];
    int b = blockIdx.x, t = threadIdx.x;
    int v = cnt_bb[b * NBLK + t];
    sm[t] = v;
    __syncthreads();
    for (int o = 1; o < NBLK; o <<= 1) {
        int u = (t >= o) ? sm[t - o] : 0;
        __syncthreads();
        sm[t] += u;
        __syncthreads();
    }
    cnt_bb[b * NBLK + t] = sm[t] - v;
    if (t == NBLK - 1) btot[b] = sm[t];
}

// blocks 0..7: W1 -> fragment-major bf16; block 8: scan of btot;
// block 9: W2 -> column-major bf16 (w2t[n][k]).
__global__ __launch_bounds__(512) void csr_b2_w1t(const int* __restrict__ btot,
                                                  int* __restrict__ bbase,
                                                  const float* __restrict__ W,
                                                  uint4* __restrict__ wtf,
                                                  const float* __restrict__ W2,
                                                  short* __restrict__ w2t) {
    int t = threadIdx.x;
    if (blockIdx.x < 8) {
        int j = blockIdx.x * 512 + t;
        int f = j >> 6, lane = j & 63;
        int kt = f >> 3, tt = f & 7;
        int m = lane & 15, q = lane >> 4;
        int c = tt * 16 + m;
        int k0 = kt * 32 + q * 8;
        unsigned p[4];
#pragma unroll
        for (int i = 0; i < 4; ++i)
            p[i] = packbf(W[(k0 + 2 * i) * HID + c], W[(k0 + 2 * i + 1) * HID + c]);
        uint4 v; v.x = p[0]; v.y = p[1]; v.z = p[2]; v.w = p[3];
        wtf[j] = v;
        return;
    }
    if (blockIdx.x == 9) {
        int n0 = t >> 5, k0 = (t & 31) * 4;
#pragma unroll
        for (int i = 0; i < 4; ++i)
            w2t[n0 * HID + k0 + i] = f2bf(W2[(k0 + i) * OUT_DIM + n0]);
        return;
    }
    __shared__ int sm[512];
    int v = (t < NBUCK) ? btot[t] : 0;
    sm[t] = v;
    __syncthreads();
    for (int o = 1; o < 512; o <<= 1) {
        int u = (t >= o) ? sm[t - o] : 0;
        __syncthreads();
        sm[t] += u;
        __syncthreads();
    }
    if (t < NBUCK) bbase[t] = sm[t] - v;
    if (t == 511) bbase[NBUCK] = sm[511];
}

__global__ __launch_bounds__(256) void csr_c(const int4* __restrict__ src4,
                                             const int4* __restrict__ dst4,
                                             const int* __restrict__ cnt_bb,
                                             const int* __restrict__ bbase,
                                             unsigned* __restrict__ tmp) {
    __shared__ int run[NBUCK];
    int t = threadIdx.x;
    for (int i = t; i < NBUCK; i += 256)
        run[i] = bbase[i] + cnt_bb[i * NBLK + blockIdx.x];
    __syncthreads();
    for (int i = blockIdx.x * 256 + t; i < E_EDGES / 4; i += NBLK * 256) {
        int4 d = dst4[i];
        int4 s = src4[i];
        int p0 = atomicAdd(&run[d.x >> 7], 1);
        tmp[p0] = (unsigned)s.x | ((unsigned)(d.x & 127) << 17);
        int p1 = atomicAdd(&run[d.y >> 7], 1);
        tmp[p1] = (unsigned)s.y | ((unsigned)(d.y & 127) << 17);
        int p2 = atomicAdd(&run[d.z >> 7], 1);
        tmp[p2] = (unsigned)s.z | ((unsigned)(d.z & 127) << 17);
        int p3 = atomicAdd(&run[d.w >> 7], 1);
        tmp[p3] = (unsigned)s.w | ((unsigned)(d.w & 127) << 17);
    }
}

__global__ __launch_bounds__(256) void csr_p2(const unsigned* __restrict__ tmp,
                                              const int* __restrict__ bbase,
                                              int* __restrict__ rowptr,
                                              float* __restrict__ dinv,
                                              int* __restrict__ ssrc) {
    __shared__ unsigned ed[P2CAP];
    __shared__ int cnt[128];
    __shared__ int off[128];
    int b = blockIdx.x, t = threadIdx.x;
    int base = bbase[b];
    int m = bbase[b + 1] - base;
    if (m > P2CAP) m = P2CAP;
    if (t < 128) cnt[t] = 0;
    __syncthreads();
    for (int i = t; i < m; i += 256) {
        unsigned v = tmp[base + i];
        ed[i] = v;
        atomicAdd(&cnt[v >> 17], 1);
    }
    __syncthreads();
    if (t < 128) off[t] = cnt[t];
    __syncthreads();
    for (int o = 1; o < 128; o <<= 1) {
        int u = (t >= o && t < 128) ? off[t - o] : 0;
        __syncthreads();
        if (t < 128) off[t] += u;
        __syncthreads();
    }
    if (t < 128) {
        int node = b * 128 + t;
        int ex = off[t] - cnt[t];
        if (node < N_NODES) {
            rowptr[node] = base + ex;
            dinv[node] = rsqrtf((float)(cnt[t] + 1));
        }
        off[t] = ex;
    }
    if (b == NBUCK - 1 && t == 0) rowptr[N_NODES] = E_EDGES;
    __syncthreads();
    for (int i = t; i < m; i += 256) {
        unsigned v = ed[i];
        int p = atomicAdd(&off[v >> 17], 1);
        ssrc[base + p] = (int)(v & 0x1FFFF);
    }
}

// ================= layer-1 GEMM: LDS-staged B, bf16 MFMA ====================
__global__ __launch_bounds__(512) void gemm1_mfma(const float* __restrict__ x,
                                                  const uint4* __restrict__ wtf,
                                                  const float* __restrict__ dinv,
                                                  short* __restrict__ h) {
    __shared__ uint4 lwt[64 * 64];   // 64 KB
    int tid = threadIdx.x;
#pragma unroll
    for (int i = 0; i < 8; ++i)
        lwt[i * 512 + tid] = wtf[i * 512 + tid];

    int wave = tid >> 6;
    int lane = tid & 63;
    int m = lane & 15;
    int q = lane >> 4;
    int row0 = blockIdx.x * 128 + wave * 16;
    int arow_idx = row0 + m;
    const float4* arow4 = (const float4*)(x + (size_t)(arow_idx < N_NODES ? arow_idx : 0) * IN_DIM);

    frag_ab a[8];
#pragma unroll
    for (int kt = 0; kt < 8; ++kt) {
        float4 f0 = arow4[kt * 8 + q * 2];
        float4 f1 = arow4[kt * 8 + q * 2 + 1];
        a[kt][0] = f2bf(f0.x); a[kt][1] = f2bf(f0.y); a[kt][2] = f2bf(f0.z); a[kt][3] = f2bf(f0.w);
        a[kt][4] = f2bf(f1.x); a[kt][5] = f2bf(f1.y); a[kt][6] = f2bf(f1.z); a[kt][7] = f2bf(f1.w);
    }

    frag_cd acc[8];
#pragma unroll
    for (int t = 0; t < 8; ++t) acc[t] = frag_cd{0.f, 0.f, 0.f, 0.f};

    __syncthreads();

#pragma unroll
    for (int kt = 0; kt < 8; ++kt) {
#pragma unroll
        for (int t = 0; t < 8; ++t) {
            frag_ab b = *(const frag_ab*)&lwt[(kt * 8 + t) * 64 + lane];
            acc[t] = __builtin_amdgcn_mfma_f32_16x16x32_bf16(a[kt], b, acc[t], 0, 0, 0);
        }
    }

    float dv[4];
#pragma unroll
    for (int r = 0; r < 4; ++r) {
        int orow = row0 + q * 4 + r;
        dv[r] = (orow < N_NODES) ? dinv[orow] : 0.f;
    }
#pragma unroll
    for (int t = 0; t < 8; ++t) {
#pragma unroll
        for (int r = 0; r < 4; ++r) {
            int orow = row0 + q * 4 + r;
            if (orow < N_NODES)
                h[(size_t)orow * HID + t * 16 + m] = f2bf(acc[t][r] * dv[r]);
        }
    }
}

// ===== layer-1 pull, feature-sliced + XCD-pinned ===========================
// 4 slices of 32 features; slice table = 3.2 MB, resident in one XCD's L2.
// Grid = 6250 nodegroups x 8 slots; slot = blockIdx&7 -> XCD (round-robin
// heuristic); slice = slot>>1 (XCD pair per slice), half = slot&1.
// Wave layout: eo = lane>>2 (16 edges per gather instr), g = lane&3
// (uint4 = 8 features). Reduction over eo: shfl_xor {4,8,16,32}.
__global__ __launch_bounds__(256) void agg1_pull(const short* __restrict__ h1s,
                                                 const float* __restrict__ dinv,
                                                 const float* __restrict__ b1,
                                                 const int* __restrict__ rowptr,
                                                 const int* __restrict__ ssrc,
                                                 uint4* __restrict__ out1) {
    int wave = threadIdx.x >> 6;
    int lane = threadIdx.x & 63;
    int slot  = blockIdx.x & 7;
    int nb    = blockIdx.x >> 3;
    int slice = slot >> 1;
    int half  = slot & 1;
    int node = __builtin_amdgcn_readfirstlane(nb * 8 + half * 4 + wave);
    if (node >= N_NODES) return;
    int eo = lane >> 2;       // edge slot: 16 edges per iteration
    int g  = lane & 3;        // feature octet within slice

    const short* base = h1s + slice * 32 + g * 8;
    int lo = rowptr[node], hi = rowptr[node + 1];
    float dd = dinv[node];
    float a0 = 0.f, a1 = 0.f, a2 = 0.f, a3 = 0.f;
    float a4 = 0.f, a5 = 0.f, a6 = 0.f, a7 = 0.f;

    if (eo == 0) {   // self-loop row (slice)
        uint4 u = *(const uint4*)(base + (size_t)node * HID);
        a0 = bflo(u.x); a1 = bfhi(u.x); a2 = bflo(u.y); a3 = bfhi(u.y);
        a4 = bflo(u.z); a5 = bfhi(u.z); a6 = bflo(u.w); a7 = bfhi(u.w);
    }

    int e = lo;
    for (; e + 32 <= hi; e += 32) {   // 2 independent 16-edge gathers
        int s0 = ssrc[e + eo];
        int s1 = ssrc[e + 16 + eo];
        uint4 u0 = *(const uint4*)(base + (size_t)s0 * HID);
        uint4 u1 = *(const uint4*)(base + (size_t)s1 * HID);
        a0 += bflo(u0.x); a1 += bfhi(u0.x); a2 += bflo(u0.y); a3 += bfhi(u0.y);
        a4 += bflo(u0.z); a5 += bfhi(u0.z); a6 += bflo(u0.w); a7 += bfhi(u0.w);
        a0 += bflo(u1.x); a1 += bfhi(u1.x); a2 += bflo(u1.y); a3 += bfhi(u1.y);
        a4 += bflo(u1.z); a5 += bfhi(u1.z); a6 += bflo(u1.w); a7 += bfhi(u1.w);
    }
    for (; e + 16 <= hi; e += 16) {
        int s = ssrc[e + eo];
        uint4 u = *(const uint4*)(base + (size_t)s * HID);
        a0 += bflo(u.x); a1 += bfhi(u.x); a2 += bflo(u.y); a3 += bfhi(u.y);
        a4 += bflo(u.z); a5 += bfhi(u.z); a6 += bflo(u.w); a7 += bfhi(u.w);
    }
    if (eo < hi - e) {   // 0..15 leftover edges
        int s = ssrc[e + eo];
        uint4 u = *(const uint4*)(base + (size_t)s * HID);
        a0 += bflo(u.x); a1 += bfhi(u.x); a2 += bflo(u.y); a3 += bfhi(u.y);
        a4 += bflo(u.z); a5 += bfhi(u.z); a6 += bflo(u.w); a7 += bfhi(u.w);
    }

#pragma unroll
    for (int msk = 4; msk <= 32; msk <<= 1) {
        a0 += __shfl_xor(a0, msk); a1 += __shfl_xor(a1, msk);
        a2 += __shfl_xor(a2, msk); a3 += __shfl_xor(a3, msk);
        a4 += __shfl_xor(a4, msk); a5 += __shfl_xor(a5, msk);
        a6 += __shfl_xor(a6, msk); a7 += __shfl_xor(a7, msk);
    }

    if (eo == 0) {
        const float* bs = b1 + slice * 32 + g * 8;
        float4 bA = *(const float4*)bs;
        float4 bB = *(const float4*)(bs + 4);
        float o0 = fmaxf(fmaf(dd, a0, bA.x), 0.f);
        float o1 = fmaxf(fmaf(dd, a1, bA.y), 0.f);
        float o2 = fmaxf(fmaf(dd, a2, bA.z), 0.f);
        float o3 = fmaxf(fmaf(dd, a3, bA.w), 0.f);
        float o4 = fmaxf(fmaf(dd, a4, bB.x), 0.f);
        float o5 = fmaxf(fmaf(dd, a5, bB.y), 0.f);
        float o6 = fmaxf(fmaf(dd, a6, bB.z), 0.f);
        float o7 = fmaxf(fmaf(dd, a7, bB.w), 0.f);
        uint4 st;
        st.x = packbf(o0, o1); st.y = packbf(o2, o3);
        st.z = packbf(o4, o5); st.w = packbf(o6, o7);
        out1[(size_t)node * 16 + slice * 4 + g] = st;
    }
}

// ===== layer-2 transform via MFMA: h2s = (out1 @ W2) * dinv, bf16 out ======
__global__ __launch_bounds__(256) void gemm2_mfma(const short* __restrict__ out1,
                                                  const short* __restrict__ w2t,
                                                  const float* __restrict__ dinv,
                                                  short* __restrict__ h2s) {
    int wave = threadIdx.x >> 6;
    int lane = threadIdx.x & 63;
    int m = lane & 15;
    int q = lane >> 4;
    int row0 = blockIdx.x * 64 + wave * 16;
    int arow = row0 + m;
    if (arow >= N_NODES) arow = N_NODES - 1;   // clamp loads
    const short* ap = out1 + (size_t)arow * HID + q * 8;
    const short* bp = w2t + m * HID + q * 8;

    frag_cd acc = frag_cd{0.f, 0.f, 0.f, 0.f};
#pragma unroll
    for (int kt = 0; kt < 4; ++kt) {
        frag_ab a = *(const frag_ab*)(ap + kt * 32);
        frag_ab b = *(const frag_ab*)(bp + kt * 32);
        acc = __builtin_amdgcn_mfma_f32_16x16x32_bf16(a, b, acc, 0, 0, 0);
    }
#pragma unroll
    for (int r = 0; r < 4; ++r) {
        int row = row0 + q * 4 + r;
        if (row < N_NODES)
            h2s[(size_t)row * OUT_DIM + m] = f2bf(acc[r] * dinv[row]);
    }
}

// ===== layer-2 pull (bf16 rows, 16 edges/iter) + bias + log_softmax ========
__global__ __launch_bounds__(256) void agg2_pull(const unsigned* __restrict__ h2s,
                                                 const float* __restrict__ dinv,
                                                 const float* __restrict__ b2,
                                                 const int* __restrict__ rowptr,
                                                 const int* __restrict__ ssrc,
                                                 float* __restrict__ out) {
    int wave = threadIdx.x >> 6;
    int lane = threadIdx.x & 63;
    int node = __builtin_amdgcn_readfirstlane(blockIdx.x * 4 + wave);
    if (node >= N_NODES) return;
    int eo = lane >> 3;
    int g  = lane & 7;

    int lo = rowptr[node], hi = rowptr[node + 1];
    float a0 = 0.f, a1 = 0.f;
    if (eo == 0) {
        unsigned u = h2s[(size_t)node * 8 + g];
        a0 = bflo(u); a1 = bfhi(u);
    }
    int e = lo;
    for (; e + 16 <= hi; e += 16) {
        int s0 = ssrc[e + eo];
        int s1 = ssrc[e + 8 + eo];
        unsigned u0 = h2s[(size_t)s0 * 8 + g];
        unsigned u1 = h2s[(size_t)s1 * 8 + g];
        a0 += bflo(u0); a1 += bfhi(u0);
        a0 += bflo(u1); a1 += bfhi(u1);
    }
    for (; e + 8 <= hi; e += 8) {
        int s = ssrc[e + eo];
        unsigned u = h2s[(size_t)s * 8 + g];
        a0 += bflo(u); a1 += bfhi(u);
    }
    if (eo < hi - e) {
        int s = ssrc[e + eo];
        unsigned u = h2s[(size_t)s * 8 + g];
        a0 += bflo(u); a1 += bfhi(u);
    }

    a0 += __shfl_xor(a0, 8);  a1 += __shfl_xor(a1, 8);
    a0 += __shfl_xor(a0, 16); a1 += __shfl_xor(a1, 16);
    a0 += __shfl_xor(a0, 32); a1 += __shfl_xor(a1, 32);

    float dd = dinv[node];
    float2 bb = *(const float2*)(b2 + 2 * g);
    float v0 = fmaf(dd, a0, bb.x);
    float v1 = fmaf(dd, a1, bb.y);

    float m = fmaxf(v0, v1);
#pragma unroll
    for (int msk = 1; msk < 8; msk <<= 1) m = fmaxf(m, __shfl_xor(m, msk));
    float s2 = __expf(v0 - m) + __expf(v1 - m);
#pragma unroll
    for (int msk = 1; msk < 8; msk <<= 1) s2 += __shfl_xor(s2, msk);
    float lse = m + __logf(s2);
    if (eo == 0) {
        float2 o; o.x = v0 - lse; o.y = v1 - lse;
        *(float2*)(out + (size_t)node * OUT_DIM + 2 * g) = o;
    }
}

extern "C" void kernel_launch(void* const* d_in, const int* in_sizes, int n_in,
                              void* d_out, int out_size, void* d_ws, size_t ws_size,
                              hipStream_t stream) {
    const float* x  = (const float*)d_in[0];
    const int*   ei = (const int*)d_in[1];
    const float* W1 = (const float*)d_in[2];
    const float* b1 = (const float*)d_in[3];
    const float* W2 = (const float*)d_in[4];
    const float* b2 = (const float*)d_in[5];
    float* out = (float*)d_out;

    const int n = N_NODES;
    const int e = E_EDGES;
    const int* srcp = ei;        // edge_index[0]
    const int* dstp = ei + e;    // edge_index[1]

    // workspace layout
    char* w = (char*)d_ws;
    int*      cnt_bb = (int*)w;        w += (size_t)NBUCK * NBLK * 4;
    int*      btot   = (int*)w;        w += (size_t)NBUCK * 4;
    int*      bbase  = (int*)w;        w += (size_t)(NBUCK + 1) * 4;
    int*      rowptr = (int*)w;        w += (size_t)(n + 1) * 4;
    float*    dinv   = (float*)w;      w += (size_t)n * 4;
    unsigned* tmp    = (unsigned*)w;   w += (size_t)e * 4;
    int*      ssrc   = (int*)w;        w += (size_t)e * 4;
    uint4*    wtf    = (uint4*)w;      w += (size_t)64 * 64 * 16;   // frag-major bf16 W1
    short*    w2t    = (short*)w;      w += (size_t)OUT_DIM * HID * 2;  // col-major bf16 W2
    short*    h1s    = (short*)w;      w += (size_t)n * HID * 2;    // bf16, pre-scaled
    short*    out1   = (short*)w;      w += (size_t)n * HID * 2;    // bf16 relu'd layer-1 out
    short*    h2s    = (short*)w;      w += (size_t)n * OUT_DIM * 2; // bf16

    auto blk = [](long long total, int b) { return (int)((total + b - 1) / b); };

    // CSR build (bucketed counting sort; also produces rowptr + dinv);
    // W1/W2 transposes piggyback on the csr_b2 launch (independent blocks).
    csr_a<<<NBLK, 256, 0, stream>>>((const int4*)dstp, cnt_bb);
    csr_b1<<<NBUCK, NBLK, 0, stream>>>(cnt_bb, btot);
    csr_b2_w1t<<<10, 512, 0, stream>>>(btot, bbase, W1, wtf, W2, w2t);
    csr_c<<<NBLK, 256, 0, stream>>>((const int4*)srcp, (const int4*)dstp, cnt_bb, bbase, tmp);
    csr_p2<<<NBUCK, 256, 0, stream>>>(tmp, bbase, rowptr, dinv, ssrc);

    // layer 1
    gemm1_mfma<<<blk(n, 128), 512, 0, stream>>>(x, wtf, dinv, h1s);
    // 6250 nodegroups x 8 slots (slice*2 + half); slot -> XCD via %8 round-robin
    agg1_pull<<<6250 * 8, 256, 0, stream>>>(h1s, dinv, b1, rowptr, ssrc, (uint4*)out1);

    // layer 2
    gemm2_mfma<<<blk(n, 64), 256, 0, stream>>>(out1, w2t, dinv, h2s);
    agg2_pull<<<blk(n, 4), 256, 0, stream>>>((const unsigned*)h2s, dinv, b2, rowptr, ssrc, out);
}

// Round 13
// 191.267 us; speedup vs baseline: 1.1859x; 1.1859x over previous
//
#include <hip/hip_runtime.h>
#include <hip/hip_bf16.h>

#define N_NODES 50000
#define E_EDGES 800000
#define IN_DIM  256
#define HID     128
#define OUT_DIM 16

#define NBUCK 391    // ceil(50000/128) buckets of 128 nodes (dst>>7)
#define NBLK  128    // blocks for bucket phases A/C
#define P2CAP 4096   // max edges per bucket (mean 2046, sigma ~45)

using frag_ab = __attribute__((ext_vector_type(8))) short;  // 8 bf16
using frag_cd = __attribute__((ext_vector_type(4))) float;  // 4 fp32

static __device__ inline short f2bf(float f) {
    union { float f; unsigned u; } v; v.f = f;
    unsigned r = (v.u + 0x7fffu + ((v.u >> 16) & 1u)) >> 16;
    return (short)r;
}
static __device__ inline float bflo(unsigned u) {
    union { unsigned u; float f; } v; v.u = u << 16; return v.f;
}
static __device__ inline float bfhi(unsigned u) {
    union { unsigned u; float f; } v; v.u = u & 0xffff0000u; return v.f;
}
static __device__ inline unsigned packbf(float a, float b) {
    return (unsigned)(unsigned short)f2bf(a) | ((unsigned)(unsigned short)f2bf(b) << 16);
}

// ================= CSR build: 2-level bucketed counting sort =================

__global__ __launch_bounds__(256) void csr_a(const int4* __restrict__ dst4,
                                             int* __restrict__ cnt_bb) {
    __shared__ int h[NBUCK];
    int t = threadIdx.x;
    for (int i = t; i < NBUCK; i += 256) h[i] = 0;
    __syncthreads();
    for (int i = blockIdx.x * 256 + t; i < E_EDGES / 4; i += NBLK * 256) {
        int4 d = dst4[i];
        atomicAdd(&h[d.x >> 7], 1);
        atomicAdd(&h[d.y >> 7], 1);
        atomicAdd(&h[d.z >> 7], 1);
        atomicAdd(&h[d.w >> 7], 1);
    }
    __syncthreads();
    for (int i = t; i < NBUCK; i += 256) cnt_bb[i * NBLK + blockIdx.x] = h[i];
}

__global__ __launch_bounds__(NBLK) void csr_b1(int* __restrict__ cnt_bb,
                                               int* __restrict__ btot) {
    __shared__ int sm[NBLK];
    int b = blockIdx.x, t = threadIdx.x;
    int v = cnt_bb[b * NBLK + t];
    sm[t] = v;
    __syncthreads();
    for (int o = 1; o < NBLK; o <<= 1) {
        int u = (t >= o) ? sm[t - o] : 0;
        __syncthreads();
        sm[t] += u;
        __syncthreads();
    }
    cnt_bb[b * NBLK + t] = sm[t] - v;
    if (t == NBLK - 1) btot[b] = sm[t];
}

// blocks 0..7: W1 -> fragment-major bf16; block 8: scan of btot;
// block 9: W2 -> column-major bf16 (w2t[n][k]).
__global__ __launch_bounds__(512) void csr_b2_w1t(const int* __restrict__ btot,
                                                  int* __restrict__ bbase,
                                                  const float* __restrict__ W,
                                                  uint4* __restrict__ wtf,
                                                  const float* __restrict__ W2,
                                                  short* __restrict__ w2t) {
    int t = threadIdx.x;
    if (blockIdx.x < 8) {
        int j = blockIdx.x * 512 + t;
        int f = j >> 6, lane = j & 63;
        int kt = f >> 3, tt = f & 7;
        int m = lane & 15, q = lane >> 4;
        int c = tt * 16 + m;
        int k0 = kt * 32 + q * 8;
        unsigned p[4];
#pragma unroll
        for (int i = 0; i < 4; ++i)
            p[i] = packbf(W[(k0 + 2 * i) * HID + c], W[(k0 + 2 * i + 1) * HID + c]);
        uint4 v; v.x = p[0]; v.y = p[1]; v.z = p[2]; v.w = p[3];
        wtf[j] = v;
        return;
    }
    if (blockIdx.x == 9) {
        int n0 = t >> 5, k0 = (t & 31) * 4;
#pragma unroll
        for (int i = 0; i < 4; ++i)
            w2t[n0 * HID + k0 + i] = f2bf(W2[(k0 + i) * OUT_DIM + n0]);
        return;
    }
    __shared__ int sm[512];
    int v = (t < NBUCK) ? btot[t] : 0;
    sm[t] = v;
    __syncthreads();
    for (int o = 1; o < 512; o <<= 1) {
        int u = (t >= o) ? sm[t - o] : 0;
        __syncthreads();
        sm[t] += u;
        __syncthreads();
    }
    if (t < NBUCK) bbase[t] = sm[t] - v;
    if (t == 511) bbase[NBUCK] = sm[511];
}

__global__ __launch_bounds__(256) void csr_c(const int4* __restrict__ src4,
                                             const int4* __restrict__ dst4,
                                             const int* __restrict__ cnt_bb,
                                             const int* __restrict__ bbase,
                                             unsigned* __restrict__ tmp) {
    __shared__ int run[NBUCK];
    int t = threadIdx.x;
    for (int i = t; i < NBUCK; i += 256)
        run[i] = bbase[i] + cnt_bb[i * NBLK + blockIdx.x];
    __syncthreads();
    for (int i = blockIdx.x * 256 + t; i < E_EDGES / 4; i += NBLK * 256) {
        int4 d = dst4[i];
        int4 s = src4[i];
        int p0 = atomicAdd(&run[d.x >> 7], 1);
        tmp[p0] = (unsigned)s.x | ((unsigned)(d.x & 127) << 17);
        int p1 = atomicAdd(&run[d.y >> 7], 1);
        tmp[p1] = (unsigned)s.y | ((unsigned)(d.y & 127) << 17);
        int p2 = atomicAdd(&run[d.z >> 7], 1);
        tmp[p2] = (unsigned)s.z | ((unsigned)(d.z & 127) << 17);
        int p3 = atomicAdd(&run[d.w >> 7], 1);
        tmp[p3] = (unsigned)s.w | ((unsigned)(d.w & 127) << 17);
    }
}

__global__ __launch_bounds__(256) void csr_p2(const unsigned* __restrict__ tmp,
                                              const int* __restrict__ bbase,
                                              int* __restrict__ rowptr,
                                              float* __restrict__ dinv,
                                              int* __restrict__ ssrc) {
    __shared__ unsigned ed[P2CAP];
    __shared__ int cnt[128];
    __shared__ int off[128];
    int b = blockIdx.x, t = threadIdx.x;
    int base = bbase[b];
    int m = bbase[b + 1] - base;
    if (m > P2CAP) m = P2CAP;
    if (t < 128) cnt[t] = 0;
    __syncthreads();
    for (int i = t; i < m; i += 256) {
        unsigned v = tmp[base + i];
        ed[i] = v;
        atomicAdd(&cnt[v >> 17], 1);
    }
    __syncthreads();
    if (t < 128) off[t] = cnt[t];
    __syncthreads();
    for (int o = 1; o < 128; o <<= 1) {
        int u = (t >= o && t < 128) ? off[t - o] : 0;
        __syncthreads();
        if (t < 128) off[t] += u;
        __syncthreads();
    }
    if (t < 128) {
        int node = b * 128 + t;
        int ex = off[t] - cnt[t];
        if (node < N_NODES) {
            rowptr[node] = base + ex;
            dinv[node] = rsqrtf((float)(cnt[t] + 1));
        }
        off[t] = ex;
    }
    if (b == NBUCK - 1 && t == 0) rowptr[N_NODES] = E_EDGES;
    __syncthreads();
    for (int i = t; i < m; i += 256) {
        unsigned v = ed[i];
        int p = atomicAdd(&off[v >> 17], 1);
        ssrc[base + p] = (int)(v & 0x1FFFF);
    }
}

// ============ layer-1 GEMM: 32 KB LDS (split K), bf16 MFMA =================
// Staging wtf in two 32 KB halves doubles blocks/CU (LDS 64->32 KB), raising
// occupancy from 16 to 24-32 waves/CU to hide the x HBM stream.
__global__ __launch_bounds__(512) void gemm1_mfma(const float* __restrict__ x,
                                                  const uint4* __restrict__ wtf,
                                                  const float* __restrict__ dinv,
                                                  short* __restrict__ h) {
    __shared__ uint4 lwt[32 * 64];   // 32 KB
    int tid = threadIdx.x;
    int wave = tid >> 6;
    int lane = tid & 63;
    int m = lane & 15;
    int q = lane >> 4;
    int row0 = blockIdx.x * 128 + wave * 16;
    int arow_idx = row0 + m;
    const float4* arow4 = (const float4*)(x + (size_t)(arow_idx < N_NODES ? arow_idx : 0) * IN_DIM);

    frag_ab a[8];
#pragma unroll
    for (int kt = 0; kt < 8; ++kt) {
        float4 f0 = arow4[kt * 8 + q * 2];
        float4 f1 = arow4[kt * 8 + q * 2 + 1];
        a[kt][0] = f2bf(f0.x); a[kt][1] = f2bf(f0.y); a[kt][2] = f2bf(f0.z); a[kt][3] = f2bf(f0.w);
        a[kt][4] = f2bf(f1.x); a[kt][5] = f2bf(f1.y); a[kt][6] = f2bf(f1.z); a[kt][7] = f2bf(f1.w);
    }

    frag_cd acc[8];
#pragma unroll
    for (int t = 0; t < 8; ++t) acc[t] = frag_cd{0.f, 0.f, 0.f, 0.f};

    // pass 0: fragments 0..31 (kt 0..3)
#pragma unroll
    for (int i = 0; i < 4; ++i)
        lwt[i * 512 + tid] = wtf[i * 512 + tid];
    __syncthreads();
#pragma unroll
    for (int kt = 0; kt < 4; ++kt) {
#pragma unroll
        for (int t = 0; t < 8; ++t) {
            frag_ab b = *(const frag_ab*)&lwt[(kt * 8 + t) * 64 + lane];
            acc[t] = __builtin_amdgcn_mfma_f32_16x16x32_bf16(a[kt], b, acc[t], 0, 0, 0);
        }
    }
    __syncthreads();
    // pass 1: fragments 32..63 (kt 4..7)
#pragma unroll
    for (int i = 0; i < 4; ++i)
        lwt[i * 512 + tid] = wtf[2048 + i * 512 + tid];
    __syncthreads();
#pragma unroll
    for (int kt = 4; kt < 8; ++kt) {
#pragma unroll
        for (int t = 0; t < 8; ++t) {
            frag_ab b = *(const frag_ab*)&lwt[((kt - 4) * 8 + t) * 64 + lane];
            acc[t] = __builtin_amdgcn_mfma_f32_16x16x32_bf16(a[kt], b, acc[t], 0, 0, 0);
        }
    }

    float dv[4];
#pragma unroll
    for (int r = 0; r < 4; ++r) {
        int orow = row0 + q * 4 + r;
        dv[r] = (orow < N_NODES) ? dinv[orow] : 0.f;
    }
#pragma unroll
    for (int t = 0; t < 8; ++t) {
#pragma unroll
        for (int r = 0; r < 4; ++r) {
            int orow = row0 + q * 4 + r;
            if (orow < N_NODES)
                h[(size_t)orow * HID + t * 16 + m] = f2bf(acc[t][r] * dv[r]);
        }
    }
}

// ===== layer-1 pull: gather + reduce + bias/ReLU -> bf16 out1 (no LDS) =====
// At the measured random-gather ceiling (~111 MB L2-miss @ ~2.4 TB/s).
__global__ __launch_bounds__(256) void agg1_pull(const short* __restrict__ h1s,
                                                 const float* __restrict__ dinv,
                                                 const float* __restrict__ b1,
                                                 const int* __restrict__ rowptr,
                                                 const int* __restrict__ ssrc,
                                                 uint4* __restrict__ out1) {
    int wave = threadIdx.x >> 6;
    int lane = threadIdx.x & 63;
    int node = __builtin_amdgcn_readfirstlane(blockIdx.x * 4 + wave);
    if (node >= N_NODES) return;
    int eo = lane >> 4;       // edge slot in quad
    int g  = lane & 15;       // feature octet

    int lo = rowptr[node], hi = rowptr[node + 1];
    float dd = dinv[node];
    float a0 = 0.f, a1 = 0.f, a2 = 0.f, a3 = 0.f;
    float a4 = 0.f, a5 = 0.f, a6 = 0.f, a7 = 0.f;

    if (eo == 0) {   // self-loop row
        uint4 u = *(const uint4*)(h1s + (size_t)node * HID + g * 8);
        a0 = bflo(u.x); a1 = bfhi(u.x); a2 = bflo(u.y); a3 = bfhi(u.y);
        a4 = bflo(u.z); a5 = bfhi(u.z); a6 = bflo(u.w); a7 = bfhi(u.w);
    }

    int e = lo;
    for (; e + 16 <= hi; e += 16) {
        int s0 = ssrc[e + eo];
        int s1 = ssrc[e + 4 + eo];
        int s2 = ssrc[e + 8 + eo];
        int s3 = ssrc[e + 12 + eo];
        uint4 u0 = *(const uint4*)(h1s + (size_t)s0 * HID + g * 8);
        uint4 u1 = *(const uint4*)(h1s + (size_t)s1 * HID + g * 8);
        uint4 u2 = *(const uint4*)(h1s + (size_t)s2 * HID + g * 8);
        uint4 u3 = *(const uint4*)(h1s + (size_t)s3 * HID + g * 8);
        a0 += bflo(u0.x); a1 += bfhi(u0.x); a2 += bflo(u0.y); a3 += bfhi(u0.y);
        a4 += bflo(u0.z); a5 += bfhi(u0.z); a6 += bflo(u0.w); a7 += bfhi(u0.w);
        a0 += bflo(u1.x); a1 += bfhi(u1.x); a2 += bflo(u1.y); a3 += bfhi(u1.y);
        a4 += bflo(u1.z); a5 += bfhi(u1.z); a6 += bflo(u1.w); a7 += bfhi(u1.w);
        a0 += bflo(u2.x); a1 += bfhi(u2.x); a2 += bflo(u2.y); a3 += bfhi(u2.y);
        a4 += bflo(u2.z); a5 += bfhi(u2.z); a6 += bflo(u2.w); a7 += bfhi(u2.w);
        a0 += bflo(u3.x); a1 += bfhi(u3.x); a2 += bflo(u3.y); a3 += bfhi(u3.y);
        a4 += bflo(u3.z); a5 += bfhi(u3.z); a6 += bflo(u3.w); a7 += bfhi(u3.w);
    }
    for (; e + 4 <= hi; e += 4) {
        int s = ssrc[e + eo];
        uint4 u = *(const uint4*)(h1s + (size_t)s * HID + g * 8);
        a0 += bflo(u.x); a1 += bfhi(u.x); a2 += bflo(u.y); a3 += bfhi(u.y);
        a4 += bflo(u.z); a5 += bfhi(u.z); a6 += bflo(u.w); a7 += bfhi(u.w);
    }
    if (eo < hi - e) {
        int s = ssrc[e + eo];
        uint4 u = *(const uint4*)(h1s + (size_t)s * HID + g * 8);
        a0 += bflo(u.x); a1 += bfhi(u.x); a2 += bflo(u.y); a3 += bfhi(u.y);
        a4 += bflo(u.z); a5 += bfhi(u.z); a6 += bflo(u.w); a7 += bfhi(u.w);
    }

    a0 += __shfl_xor(a0, 16); a1 += __shfl_xor(a1, 16);
    a2 += __shfl_xor(a2, 16); a3 += __shfl_xor(a3, 16);
    a4 += __shfl_xor(a4, 16); a5 += __shfl_xor(a5, 16);
    a6 += __shfl_xor(a6, 16); a7 += __shfl_xor(a7, 16);
    a0 += __shfl_xor(a0, 32); a1 += __shfl_xor(a1, 32);
    a2 += __shfl_xor(a2, 32); a3 += __shfl_xor(a3, 32);
    a4 += __shfl_xor(a4, 32); a5 += __shfl_xor(a5, 32);
    a6 += __shfl_xor(a6, 32); a7 += __shfl_xor(a7, 32);

    if (eo == 0) {
        float4 bA = *(const float4*)(b1 + g * 8);
        float4 bB = *(const float4*)(b1 + g * 8 + 4);
        float o0 = fmaxf(fmaf(dd, a0, bA.x), 0.f);
        float o1 = fmaxf(fmaf(dd, a1, bA.y), 0.f);
        float o2 = fmaxf(fmaf(dd, a2, bA.z), 0.f);
        float o3 = fmaxf(fmaf(dd, a3, bA.w), 0.f);
        float o4 = fmaxf(fmaf(dd, a4, bB.x), 0.f);
        float o5 = fmaxf(fmaf(dd, a5, bB.y), 0.f);
        float o6 = fmaxf(fmaf(dd, a6, bB.z), 0.f);
        float o7 = fmaxf(fmaf(dd, a7, bB.w), 0.f);
        uint4 st;
        st.x = packbf(o0, o1); st.y = packbf(o2, o3);
        st.z = packbf(o4, o5); st.w = packbf(o6, o7);
        out1[(size_t)node * 16 + g] = st;
    }
}

// ===== layer-2 transform via MFMA: h2s = (out1 @ W2) * dinv, bf16 out ======
__global__ __launch_bounds__(256) void gemm2_mfma(const short* __restrict__ out1,
                                                  const short* __restrict__ w2t,
                                                  const float* __restrict__ dinv,
                                                  short* __restrict__ h2s) {
    int wave = threadIdx.x >> 6;
    int lane = threadIdx.x & 63;
    int m = lane & 15;
    int q = lane >> 4;
    int row0 = blockIdx.x * 64 + wave * 16;
    int arow = row0 + m;
    if (arow >= N_NODES) arow = N_NODES - 1;   // clamp loads
    const short* ap = out1 + (size_t)arow * HID + q * 8;
    const short* bp = w2t + m * HID + q * 8;

    frag_cd acc = frag_cd{0.f, 0.f, 0.f, 0.f};
#pragma unroll
    for (int kt = 0; kt < 4; ++kt) {
        frag_ab a = *(const frag_ab*)(ap + kt * 32);
        frag_ab b = *(const frag_ab*)(bp + kt * 32);
        acc = __builtin_amdgcn_mfma_f32_16x16x32_bf16(a, b, acc, 0, 0, 0);
    }
#pragma unroll
    for (int r = 0; r < 4; ++r) {
        int row = row0 + q * 4 + r;
        if (row < N_NODES)
            h2s[(size_t)row * OUT_DIM + m] = f2bf(acc[r] * dinv[row]);
    }
}

// ===== layer-2 pull (bf16 rows, 16 edges/iter) + bias + log_softmax ========
__global__ __launch_bounds__(256) void agg2_pull(const unsigned* __restrict__ h2s,
                                                 const float* __restrict__ dinv,
                                                 const float* __restrict__ b2,
                                                 const int* __restrict__ rowptr,
                                                 const int* __restrict__ ssrc,
                                                 float* __restrict__ out) {
    int wave = threadIdx.x >> 6;
    int lane = threadIdx.x & 63;
    int node = __builtin_amdgcn_readfirstlane(blockIdx.x * 4 + wave);
    if (node >= N_NODES) return;
    int eo = lane >> 3;
    int g  = lane & 7;

    int lo = rowptr[node], hi = rowptr[node + 1];
    float a0 = 0.f, a1 = 0.f;
    if (eo == 0) {
        unsigned u = h2s[(size_t)node * 8 + g];
        a0 = bflo(u); a1 = bfhi(u);
    }
    int e = lo;
    for (; e + 16 <= hi; e += 16) {
        int s0 = ssrc[e + eo];
        int s1 = ssrc[e + 8 + eo];
        unsigned u0 = h2s[(size_t)s0 * 8 + g];
        unsigned u1 = h2s[(size_t)s1 * 8 + g];
        a0 += bflo(u0); a1 += bfhi(u0);
        a0 += bflo(u1); a1 += bfhi(u1);
    }
    for (; e + 8 <= hi; e += 8) {
        int s = ssrc[e + eo];
        unsigned u = h2s[(size_t)s * 8 + g];
        a0 += bflo(u); a1 += bfhi(u);
    }
    if (eo < hi - e) {
        int s = ssrc[e + eo];
        unsigned u = h2s[(size_t)s * 8 + g];
        a0 += bflo(u); a1 += bfhi(u);
    }

    a0 += __shfl_xor(a0, 8);  a1 += __shfl_xor(a1, 8);
    a0 += __shfl_xor(a0, 16); a1 += __shfl_xor(a1, 16);
    a0 += __shfl_xor(a0, 32); a1 += __shfl_xor(a1, 32);

    float dd = dinv[node];
    float2 bb = *(const float2*)(b2 + 2 * g);
    float v0 = fmaf(dd, a0, bb.x);
    float v1 = fmaf(dd, a1, bb.y);

    float m = fmaxf(v0, v1);
#pragma unroll
    for (int msk = 1; msk < 8; msk <<= 1) m = fmaxf(m, __shfl_xor(m, msk));
    float s2 = __expf(v0 - m) + __expf(v1 - m);
#pragma unroll
    for (int msk = 1; msk < 8; msk <<= 1) s2 += __shfl_xor(s2, msk);
    float lse = m + __logf(s2);
    if (eo == 0) {
        float2 o; o.x = v0 - lse; o.y = v1 - lse;
        *(float2*)(out + (size_t)node * OUT_DIM + 2 * g) = o;
    }
}

extern "C" void kernel_launch(void* const* d_in, const int* in_sizes, int n_in,
                              void* d_out, int out_size, void* d_ws, size_t ws_size,
                              hipStream_t stream) {
    const float* x  = (const float*)d_in[0];
    const int*   ei = (const int*)d_in[1];
    const float* W1 = (const float*)d_in[2];
    const float* b1 = (const float*)d_in[3];
    const float* W2 = (const float*)d_in[4];
    const float* b2 = (const float*)d_in[5];
    float* out = (float*)d_out;

    const int n = N_NODES;
    const int e = E_EDGES;
    const int* srcp = ei;        // edge_index[0]
    const int* dstp = ei + e;    // edge_index[1]

    // workspace layout
    char* w = (char*)d_ws;
    int*      cnt_bb = (int*)w;        w += (size_t)NBUCK * NBLK * 4;
    int*      btot   = (int*)w;        w += (size_t)NBUCK * 4;
    int*      bbase  = (int*)w;        w += (size_t)(NBUCK + 1) * 4;
    int*      rowptr = (int*)w;        w += (size_t)(n + 1) * 4;
    float*    dinv   = (float*)w;      w += (size_t)n * 4;
    unsigned* tmp    = (unsigned*)w;   w += (size_t)e * 4;
    int*      ssrc   = (int*)w;        w += (size_t)e * 4;
    uint4*    wtf    = (uint4*)w;      w += (size_t)64 * 64 * 16;   // frag-major bf16 W1
    short*    w2t    = (short*)w;      w += (size_t)OUT_DIM * HID * 2;  // col-major bf16 W2
    short*    h1s    = (short*)w;      w += (size_t)n * HID * 2;    // bf16, pre-scaled
    short*    out1   = (short*)w;      w += (size_t)n * HID * 2;    // bf16 relu'd layer-1 out
    short*    h2s    = (short*)w;      w += (size_t)n * OUT_DIM * 2; // bf16

    auto blk = [](long long total, int b) { return (int)((total + b - 1) / b); };

    // CSR build (bucketed counting sort; also produces rowptr + dinv);
    // W1/W2 transposes piggyback on the csr_b2 launch (independent blocks).
    csr_a<<<NBLK, 256, 0, stream>>>((const int4*)dstp, cnt_bb);
    csr_b1<<<NBUCK, NBLK, 0, stream>>>(cnt_bb, btot);
    csr_b2_w1t<<<10, 512, 0, stream>>>(btot, bbase, W1, wtf, W2, w2t);
    csr_c<<<NBLK, 256, 0, stream>>>((const int4*)srcp, (const int4*)dstp, cnt_bb, bbase, tmp);
    csr_p2<<<NBUCK, 256, 0, stream>>>(tmp, bbase, rowptr, dinv, ssrc);

    // layer 1
    gemm1_mfma<<<blk(n, 128), 512, 0, stream>>>(x, wtf, dinv, h1s);
    agg1_pull<<<blk(n, 4), 256, 0, stream>>>(h1s, dinv, b1, rowptr, ssrc, (uint4*)out1);

    // layer 2
    gemm2_mfma<<<blk(n, 64), 256, 0, stream>>>(out1, w2t, dinv, h2s);
    agg2_pull<<<blk(n, 4), 256, 0, stream>>>((const unsigned*)h2s, dinv, b2, rowptr, ssrc, out);
}

// Round 14
// 190.839 us; speedup vs baseline: 1.1885x; 1.0022x over previous
//
#include <hip/hip_runtime.h>
#include <hip/hip_bf16.h>

#define N_NODES 50000
#define E_EDGES 800000
#define IN_DIM  256
#define HID     128
#define OUT_DIM 16

#define NBUCK 391    // ceil(50000/128) buckets of 128 nodes (dst>>7)
#define NBLK  128    // blocks for bucket phases A/C
#define P2CAP 4096   // max edges per bucket (mean 2046, sigma ~45)

using frag_ab = __attribute__((ext_vector_type(8))) short;  // 8 bf16
using frag_cd = __attribute__((ext_vector_type(4))) float;  // 4 fp32

static __device__ inline short f2bf(float f) {
    union { float f; unsigned u; } v; v.f = f;
    unsigned r = (v.u + 0x7fffu + ((v.u >> 16) & 1u)) >> 16;
    return (short)r;
}
static __device__ inline float bflo(unsigned u) {
    union { unsigned u; float f; } v; v.u = u << 16; return v.f;
}
static __device__ inline float bfhi(unsigned u) {
    union { unsigned u; float f; } v; v.u = u & 0xffff0000u; return v.f;
}
static __device__ inline unsigned packbf(float a, float b) {
    return (unsigned)(unsigned short)f2bf(a) | ((unsigned)(unsigned short)f2bf(b) << 16);
}

// ================= CSR build: 2-level bucketed counting sort =================

__global__ __launch_bounds__(256) void csr_a(const int4* __restrict__ dst4,
                                             int* __restrict__ cnt_bb) {
    __shared__ int h[NBUCK];
    int t = threadIdx.x;
    for (int i = t; i < NBUCK; i += 256) h[i] = 0;
    __syncthreads();
    for (int i = blockIdx.x * 256 + t; i < E_EDGES / 4; i += NBLK * 256) {
        int4 d = dst4[i];
        atomicAdd(&h[d.x >> 7], 1);
        atomicAdd(&h[d.y >> 7], 1);
        atomicAdd(&h[d.z >> 7], 1);
        atomicAdd(&h[d.w >> 7], 1);
    }
    __syncthreads();
    for (int i = t; i < NBUCK; i += 256) cnt_bb[i * NBLK + blockIdx.x] = h[i];
}

__global__ __launch_bounds__(NBLK) void csr_b1(int* __restrict__ cnt_bb,
                                               int* __restrict__ btot) {
    __shared__ int sm[NBLK];
    int b = blockIdx.x, t = threadIdx.x;
    int v = cnt_bb[b * NBLK + t];
    sm[t] = v;
    __syncthreads();
    for (int o = 1; o < NBLK; o <<= 1) {
        int u = (t >= o) ? sm[t - o] : 0;
        __syncthreads();
        sm[t] += u;
        __syncthreads();
    }
    cnt_bb[b * NBLK + t] = sm[t] - v;
    if (t == NBLK - 1) btot[b] = sm[t];
}

// blocks 0..7: W1 -> fragment-major bf16; block 8: scan of btot;
// block 9: W2 -> column-major bf16 (w2t[n][k]).
__global__ __launch_bounds__(512) void csr_b2_w1t(const int* __restrict__ btot,
                                                  int* __restrict__ bbase,
                                                  const float* __restrict__ W,
                                                  uint4* __restrict__ wtf,
                                                  const float* __restrict__ W2,
                                                  short* __restrict__ w2t) {
    int t = threadIdx.x;
    if (blockIdx.x < 8) {
        int j = blockIdx.x * 512 + t;
        int f = j >> 6, lane = j & 63;
        int kt = f >> 3, tt = f & 7;
        int m = lane & 15, q = lane >> 4;
        int c = tt * 16 + m;
        int k0 = kt * 32 + q * 8;
        unsigned p[4];
#pragma unroll
        for (int i = 0; i < 4; ++i)
            p[i] = packbf(W[(k0 + 2 * i) * HID + c], W[(k0 + 2 * i + 1) * HID + c]);
        uint4 v; v.x = p[0]; v.y = p[1]; v.z = p[2]; v.w = p[3];
        wtf[j] = v;
        return;
    }
    if (blockIdx.x == 9) {
        int n0 = t >> 5, k0 = (t & 31) * 4;
#pragma unroll
        for (int i = 0; i < 4; ++i)
            w2t[n0 * HID + k0 + i] = f2bf(W2[(k0 + i) * OUT_DIM + n0]);
        return;
    }
    __shared__ int sm[512];
    int v = (t < NBUCK) ? btot[t] : 0;
    sm[t] = v;
    __syncthreads();
    for (int o = 1; o < 512; o <<= 1) {
        int u = (t >= o) ? sm[t - o] : 0;
        __syncthreads();
        sm[t] += u;
        __syncthreads();
    }
    if (t < NBUCK) bbase[t] = sm[t] - v;
    if (t == 511) bbase[NBUCK] = sm[511];
}

__global__ __launch_bounds__(256) void csr_c(const int4* __restrict__ src4,
                                             const int4* __restrict__ dst4,
                                             const int* __restrict__ cnt_bb,
                                             const int* __restrict__ bbase,
                                             unsigned* __restrict__ tmp) {
    __shared__ int run[NBUCK];
    int t = threadIdx.x;
    for (int i = t; i < NBUCK; i += 256)
        run[i] = bbase[i] + cnt_bb[i * NBLK + blockIdx.x];
    __syncthreads();
    for (int i = blockIdx.x * 256 + t; i < E_EDGES / 4; i += NBLK * 256) {
        int4 d = dst4[i];
        int4 s = src4[i];
        int p0 = atomicAdd(&run[d.x >> 7], 1);
        tmp[p0] = (unsigned)s.x | ((unsigned)(d.x & 127) << 17);
        int p1 = atomicAdd(&run[d.y >> 7], 1);
        tmp[p1] = (unsigned)s.y | ((unsigned)(d.y & 127) << 17);
        int p2 = atomicAdd(&run[d.z >> 7], 1);
        tmp[p2] = (unsigned)s.z | ((unsigned)(d.z & 127) << 17);
        int p3 = atomicAdd(&run[d.w >> 7], 1);
        tmp[p3] = (unsigned)s.w | ((unsigned)(d.w & 127) << 17);
    }
}

__global__ __launch_bounds__(256) void csr_p2(const unsigned* __restrict__ tmp,
                                              const int* __restrict__ bbase,
                                              int* __restrict__ rowptr,
                                              float* __restrict__ dinv,
                                              int* __restrict__ ssrc) {
    __shared__ unsigned ed[P2CAP];
    __shared__ int cnt[128];
    __shared__ int off[128];
    int b = blockIdx.x, t = threadIdx.x;
    int base = bbase[b];
    int m = bbase[b + 1] - base;
    if (m > P2CAP) m = P2CAP;
    if (t < 128) cnt[t] = 0;
    __syncthreads();
    for (int i = t; i < m; i += 256) {
        unsigned v = tmp[base + i];
        ed[i] = v;
        atomicAdd(&cnt[v >> 17], 1);
    }
    __syncthreads();
    if (t < 128) off[t] = cnt[t];
    __syncthreads();
    for (int o = 1; o < 128; o <<= 1) {
        int u = (t >= o && t < 128) ? off[t - o] : 0;
        __syncthreads();
        if (t < 128) off[t] += u;
        __syncthreads();
    }
    if (t < 128) {
        int node = b * 128 + t;
        int ex = off[t] - cnt[t];
        if (node < N_NODES) {
            rowptr[node] = base + ex;
            dinv[node] = rsqrtf((float)(cnt[t] + 1));
        }
        off[t] = ex;
    }
    if (b == NBUCK - 1 && t == 0) rowptr[N_NODES] = E_EDGES;
    __syncthreads();
    for (int i = t; i < m; i += 256) {
        unsigned v = ed[i];
        int p = atomicAdd(&off[v >> 17], 1);
        ssrc[base + p] = (int)(v & 0x1FFFF);
    }
}

// ================= layer-1 GEMM: LDS-staged B, bf16 MFMA ====================
__global__ __launch_bounds__(512) void gemm1_mfma(const float* __restrict__ x,
                                                  const uint4* __restrict__ wtf,
                                                  const float* __restrict__ dinv,
                                                  short* __restrict__ h) {
    __shared__ uint4 lwt[64 * 64];   // 64 KB
    int tid = threadIdx.x;
#pragma unroll
    for (int i = 0; i < 8; ++i)
        lwt[i * 512 + tid] = wtf[i * 512 + tid];

    int wave = tid >> 6;
    int lane = tid & 63;
    int m = lane & 15;
    int q = lane >> 4;
    int row0 = blockIdx.x * 128 + wave * 16;
    int arow_idx = row0 + m;
    const float4* arow4 = (const float4*)(x + (size_t)(arow_idx < N_NODES ? arow_idx : 0) * IN_DIM);

    frag_ab a[8];
#pragma unroll
    for (int kt = 0; kt < 8; ++kt) {
        float4 f0 = arow4[kt * 8 + q * 2];
        float4 f1 = arow4[kt * 8 + q * 2 + 1];
        a[kt][0] = f2bf(f0.x); a[kt][1] = f2bf(f0.y); a[kt][2] = f2bf(f0.z); a[kt][3] = f2bf(f0.w);
        a[kt][4] = f2bf(f1.x); a[kt][5] = f2bf(f1.y); a[kt][6] = f2bf(f1.z); a[kt][7] = f2bf(f1.w);
    }

    frag_cd acc[8];
#pragma unroll
    for (int t = 0; t < 8; ++t) acc[t] = frag_cd{0.f, 0.f, 0.f, 0.f};

    __syncthreads();

#pragma unroll
    for (int kt = 0; kt < 8; ++kt) {
#pragma unroll
        for (int t = 0; t < 8; ++t) {
            frag_ab b = *(const frag_ab*)&lwt[(kt * 8 + t) * 64 + lane];
            acc[t] = __builtin_amdgcn_mfma_f32_16x16x32_bf16(a[kt], b, acc[t], 0, 0, 0);
        }
    }

    float dv[4];
#pragma unroll
    for (int r = 0; r < 4; ++r) {
        int orow = row0 + q * 4 + r;
        dv[r] = (orow < N_NODES) ? dinv[orow] : 0.f;
    }
#pragma unroll
    for (int t = 0; t < 8; ++t) {
#pragma unroll
        for (int r = 0; r < 4; ++r) {
            int orow = row0 + q * 4 + r;
            if (orow < N_NODES)
                h[(size_t)orow * HID + t * 16 + m] = f2bf(acc[t][r] * dv[r]);
        }
    }
}

// ===== layer-1 pull: TWO nodes per wave (independent gather streams) =======
// pair p -> nodes 2p, 2p+1 (N even). Shared rowptr[mid] read. eo = lane>>4
// (4 edge slots), g = lane&15 (uint4 = 8 features). After xor-reduce over
// masks 16/32 every lane holds both totals; eo==0 stores n0, eo==1 stores n1.
__global__ __launch_bounds__(256) void agg1_pull(const short* __restrict__ h1s,
                                                 const float* __restrict__ dinv,
                                                 const float* __restrict__ b1,
                                                 const int* __restrict__ rowptr,
                                                 const int* __restrict__ ssrc,
                                                 uint4* __restrict__ out1) {
    int wave = threadIdx.x >> 6;
    int lane = threadIdx.x & 63;
    int pair = __builtin_amdgcn_readfirstlane(blockIdx.x * 4 + wave);
    int n0 = pair * 2;
    if (n0 >= N_NODES) return;
    int n1 = n0 + 1;                  // valid: N_NODES is even
    int eo = lane >> 4;
    int g  = lane & 15;

    int lo0 = rowptr[n0];
    int mid = rowptr[n0 + 1];
    int hi1 = rowptr[n1 + 1];
    float dd0 = dinv[n0], dd1 = dinv[n1];

    float a0 = 0.f, a1 = 0.f, a2 = 0.f, a3 = 0.f;
    float a4 = 0.f, a5 = 0.f, a6 = 0.f, a7 = 0.f;
    float c0 = 0.f, c1 = 0.f, c2 = 0.f, c3 = 0.f;
    float c4 = 0.f, c5 = 0.f, c6 = 0.f, c7 = 0.f;

    if (eo == 0) {        // self-loop of n0 -> A accs
        uint4 u = *(const uint4*)(h1s + (size_t)n0 * HID + g * 8);
        a0 = bflo(u.x); a1 = bfhi(u.x); a2 = bflo(u.y); a3 = bfhi(u.y);
        a4 = bflo(u.z); a5 = bfhi(u.z); a6 = bflo(u.w); a7 = bfhi(u.w);
    } else if (eo == 1) { // self-loop of n1 -> C accs
        uint4 u = *(const uint4*)(h1s + (size_t)n1 * HID + g * 8);
        c0 = bflo(u.x); c1 = bfhi(u.x); c2 = bflo(u.y); c3 = bfhi(u.y);
        c4 = bflo(u.z); c5 = bfhi(u.z); c6 = bflo(u.w); c7 = bfhi(u.w);
    }

    int e0 = lo0, e1 = mid;
    // interleaved: two independent 4-edge gather streams in flight
    for (; e0 + 4 <= mid && e1 + 4 <= hi1; e0 += 4, e1 += 4) {
        int s0 = ssrc[e0 + eo];
        int s1 = ssrc[e1 + eo];
        uint4 u0 = *(const uint4*)(h1s + (size_t)s0 * HID + g * 8);
        uint4 u1 = *(const uint4*)(h1s + (size_t)s1 * HID + g * 8);
        a0 += bflo(u0.x); a1 += bfhi(u0.x); a2 += bflo(u0.y); a3 += bfhi(u0.y);
        a4 += bflo(u0.z); a5 += bfhi(u0.z); a6 += bflo(u0.w); a7 += bfhi(u0.w);
        c0 += bflo(u1.x); c1 += bfhi(u1.x); c2 += bflo(u1.y); c3 += bfhi(u1.y);
        c4 += bflo(u1.z); c5 += bfhi(u1.z); c6 += bflo(u1.w); c7 += bfhi(u1.w);
    }
    for (; e0 + 4 <= mid; e0 += 4) {
        int s = ssrc[e0 + eo];
        uint4 u = *(const uint4*)(h1s + (size_t)s * HID + g * 8);
        a0 += bflo(u.x); a1 += bfhi(u.x); a2 += bflo(u.y); a3 += bfhi(u.y);
        a4 += bflo(u.z); a5 += bfhi(u.z); a6 += bflo(u.w); a7 += bfhi(u.w);
    }
    for (; e1 + 4 <= hi1; e1 += 4) {
        int s = ssrc[e1 + eo];
        uint4 u = *(const uint4*)(h1s + (size_t)s * HID + g * 8);
        c0 += bflo(u.x); c1 += bfhi(u.x); c2 += bflo(u.y); c3 += bfhi(u.y);
        c4 += bflo(u.z); c5 += bfhi(u.z); c6 += bflo(u.w); c7 += bfhi(u.w);
    }
    if (eo < mid - e0) {
        int s = ssrc[e0 + eo];
        uint4 u = *(const uint4*)(h1s + (size_t)s * HID + g * 8);
        a0 += bflo(u.x); a1 += bfhi(u.x); a2 += bflo(u.y); a3 += bfhi(u.y);
        a4 += bflo(u.z); a5 += bfhi(u.z); a6 += bflo(u.w); a7 += bfhi(u.w);
    }
    if (eo < hi1 - e1) {
        int s = ssrc[e1 + eo];
        uint4 u = *(const uint4*)(h1s + (size_t)s * HID + g * 8);
        c0 += bflo(u.x); c1 += bfhi(u.x); c2 += bflo(u.y); c3 += bfhi(u.y);
        c4 += bflo(u.z); c5 += bfhi(u.z); c6 += bflo(u.w); c7 += bfhi(u.w);
    }

#pragma unroll
    for (int msk = 16; msk <= 32; msk <<= 1) {
        a0 += __shfl_xor(a0, msk); a1 += __shfl_xor(a1, msk);
        a2 += __shfl_xor(a2, msk); a3 += __shfl_xor(a3, msk);
        a4 += __shfl_xor(a4, msk); a5 += __shfl_xor(a5, msk);
        a6 += __shfl_xor(a6, msk); a7 += __shfl_xor(a7, msk);
        c0 += __shfl_xor(c0, msk); c1 += __shfl_xor(c1, msk);
        c2 += __shfl_xor(c2, msk); c3 += __shfl_xor(c3, msk);
        c4 += __shfl_xor(c4, msk); c5 += __shfl_xor(c5, msk);
        c6 += __shfl_xor(c6, msk); c7 += __shfl_xor(c7, msk);
    }

    float4 bA = *(const float4*)(b1 + g * 8);
    float4 bB = *(const float4*)(b1 + g * 8 + 4);
    if (eo == 0) {
        uint4 st;
        st.x = packbf(fmaxf(fmaf(dd0, a0, bA.x), 0.f), fmaxf(fmaf(dd0, a1, bA.y), 0.f));
        st.y = packbf(fmaxf(fmaf(dd0, a2, bA.z), 0.f), fmaxf(fmaf(dd0, a3, bA.w), 0.f));
        st.z = packbf(fmaxf(fmaf(dd0, a4, bB.x), 0.f), fmaxf(fmaf(dd0, a5, bB.y), 0.f));
        st.w = packbf(fmaxf(fmaf(dd0, a6, bB.z), 0.f), fmaxf(fmaf(dd0, a7, bB.w), 0.f));
        out1[(size_t)n0 * 16 + g] = st;
    } else if (eo == 1) {
        uint4 st;
        st.x = packbf(fmaxf(fmaf(dd1, c0, bA.x), 0.f), fmaxf(fmaf(dd1, c1, bA.y), 0.f));
        st.y = packbf(fmaxf(fmaf(dd1, c2, bA.z), 0.f), fmaxf(fmaf(dd1, c3, bA.w), 0.f));
        st.z = packbf(fmaxf(fmaf(dd1, c4, bB.x), 0.f), fmaxf(fmaf(dd1, c5, bB.y), 0.f));
        st.w = packbf(fmaxf(fmaf(dd1, c6, bB.z), 0.f), fmaxf(fmaf(dd1, c7, bB.w), 0.f));
        out1[(size_t)n1 * 16 + g] = st;
    }
}

// ===== layer-2 transform via MFMA: h2s = (out1 @ W2) * dinv, bf16 out ======
__global__ __launch_bounds__(256) void gemm2_mfma(const short* __restrict__ out1,
                                                  const short* __restrict__ w2t,
                                                  const float* __restrict__ dinv,
                                                  short* __restrict__ h2s) {
    int wave = threadIdx.x >> 6;
    int lane = threadIdx.x & 63;
    int m = lane & 15;
    int q = lane >> 4;
    int row0 = blockIdx.x * 64 + wave * 16;
    int arow = row0 + m;
    if (arow >= N_NODES) arow = N_NODES - 1;   // clamp loads
    const short* ap = out1 + (size_t)arow * HID + q * 8;
    const short* bp = w2t + m * HID + q * 8;

    frag_cd acc = frag_cd{0.f, 0.f, 0.f, 0.f};
#pragma unroll
    for (int kt = 0; kt < 4; ++kt) {
        frag_ab a = *(const frag_ab*)(ap + kt * 32);
        frag_ab b = *(const frag_ab*)(bp + kt * 32);
        acc = __builtin_amdgcn_mfma_f32_16x16x32_bf16(a, b, acc, 0, 0, 0);
    }
#pragma unroll
    for (int r = 0; r < 4; ++r) {
        int row = row0 + q * 4 + r;
        if (row < N_NODES)
            h2s[(size_t)row * OUT_DIM + m] = f2bf(acc[r] * dinv[row]);
    }
}

// ===== layer-2 pull: 16 edges/instr (uint2 lanes) + bias + log_softmax =====
// lane = eo*4 + g; eo in [0,16) edge slot, g in [0,4) feature quad (uint2).
__global__ __launch_bounds__(256) void agg2_pull(const uint2* __restrict__ h2s2,
                                                 const float* __restrict__ dinv,
                                                 const float* __restrict__ b2,
                                                 const int* __restrict__ rowptr,
                                                 const int* __restrict__ ssrc,
                                                 float* __restrict__ out) {
    int wave = threadIdx.x >> 6;
    int lane = threadIdx.x & 63;
    int node = __builtin_amdgcn_readfirstlane(blockIdx.x * 4 + wave);
    if (node >= N_NODES) return;
    int eo = lane >> 2;       // 16 edge slots
    int g  = lane & 3;        // feature quad

    int lo = rowptr[node], hi = rowptr[node + 1];
    float a0 = 0.f, a1 = 0.f, a2 = 0.f, a3 = 0.f;
    if (eo == 0) {   // self loop
        uint2 u = h2s2[(size_t)node * 4 + g];
        a0 = bflo(u.x); a1 = bfhi(u.x); a2 = bflo(u.y); a3 = bfhi(u.y);
    }
    int e = lo;
    for (; e + 16 <= hi; e += 16) {
        int s = ssrc[e + eo];
        uint2 u = h2s2[(size_t)s * 4 + g];
        a0 += bflo(u.x); a1 += bfhi(u.x); a2 += bflo(u.y); a3 += bfhi(u.y);
    }
    if (eo < hi - e) {
        int s = ssrc[e + eo];
        uint2 u = h2s2[(size_t)s * 4 + g];
        a0 += bflo(u.x); a1 += bfhi(u.x); a2 += bflo(u.y); a3 += bfhi(u.y);
    }

#pragma unroll
    for (int msk = 4; msk <= 32; msk <<= 1) {
        a0 += __shfl_xor(a0, msk); a1 += __shfl_xor(a1, msk);
        a2 += __shfl_xor(a2, msk); a3 += __shfl_xor(a3, msk);
    }

    float dd = dinv[node];
    float4 bb = *(const float4*)(b2 + 4 * g);
    float v0 = fmaf(dd, a0, bb.x);
    float v1 = fmaf(dd, a1, bb.y);
    float v2 = fmaf(dd, a2, bb.z);
    float v3 = fmaf(dd, a3, bb.w);

    float m = fmaxf(fmaxf(v0, v1), fmaxf(v2, v3));
    m = fmaxf(m, __shfl_xor(m, 1));
    m = fmaxf(m, __shfl_xor(m, 2));
    float s4 = __expf(v0 - m) + __expf(v1 - m) + __expf(v2 - m) + __expf(v3 - m);
    s4 += __shfl_xor(s4, 1);
    s4 += __shfl_xor(s4, 2);
    float lse = m + __logf(s4);
    if (eo == 0) {
        float4 o; o.x = v0 - lse; o.y = v1 - lse; o.z = v2 - lse; o.w = v3 - lse;
        *(float4*)(out + (size_t)node * OUT_DIM + 4 * g) = o;
    }
}

extern "C" void kernel_launch(void* const* d_in, const int* in_sizes, int n_in,
                              void* d_out, int out_size, void* d_ws, size_t ws_size,
                              hipStream_t stream) {
    const float* x  = (const float*)d_in[0];
    const int*   ei = (const int*)d_in[1];
    const float* W1 = (const float*)d_in[2];
    const float* b1 = (const float*)d_in[3];
    const float* W2 = (const float*)d_in[4];
    const float* b2 = (const float*)d_in[5];
    float* out = (float*)d_out;

    const int n = N_NODES;
    const int e = E_EDGES;
    const int* srcp = ei;        // edge_index[0]
    const int* dstp = ei + e;    // edge_index[1]

    // workspace layout
    char* w = (char*)d_ws;
    int*      cnt_bb = (int*)w;        w += (size_t)NBUCK * NBLK * 4;
    int*      btot   = (int*)w;        w += (size_t)NBUCK * 4;
    int*      bbase  = (int*)w;        w += (size_t)(NBUCK + 1) * 4;
    int*      rowptr = (int*)w;        w += (size_t)(n + 1) * 4;
    float*    dinv   = (float*)w;      w += (size_t)n * 4;
    unsigned* tmp    = (unsigned*)w;   w += (size_t)e * 4;
    int*      ssrc   = (int*)w;        w += (size_t)e * 4;
    uint4*    wtf    = (uint4*)w;      w += (size_t)64 * 64 * 16;   // frag-major bf16 W1
    short*    w2t    = (short*)w;      w += (size_t)OUT_DIM * HID * 2;  // col-major bf16 W2
    short*    h1s    = (short*)w;      w += (size_t)n * HID * 2;    // bf16, pre-scaled
    short*    out1   = (short*)w;      w += (size_t)n * HID * 2;    // bf16 relu'd layer-1 out
    short*    h2s    = (short*)w;      w += (size_t)n * OUT_DIM * 2; // bf16

    auto blk = [](long long total, int b) { return (int)((total + b - 1) / b); };

    // CSR build (bucketed counting sort; also produces rowptr + dinv);
    // W1/W2 transposes piggyback on the csr_b2 launch (independent blocks).
    csr_a<<<NBLK, 256, 0, stream>>>((const int4*)dstp, cnt_bb);
    csr_b1<<<NBUCK, NBLK, 0, stream>>>(cnt_bb, btot);
    csr_b2_w1t<<<10, 512, 0, stream>>>(btot, bbase, W1, wtf, W2, w2t);
    csr_c<<<NBLK, 256, 0, stream>>>((const int4*)srcp, (const int4*)dstp, cnt_bb, bbase, tmp);
    csr_p2<<<NBUCK, 256, 0, stream>>>(tmp, bbase, rowptr, dinv, ssrc);

    // layer 1
    gemm1_mfma<<<blk(n, 128), 512, 0, stream>>>(x, wtf, dinv, h1s);
    agg1_pull<<<blk(n / 2, 4), 256, 0, stream>>>(h1s, dinv, b1, rowptr, ssrc, (uint4*)out1);

    // layer 2
    gemm2_mfma<<<blk(n, 64), 256, 0, stream>>>(out1, w2t, dinv, h2s);
    agg2_pull<<<blk(n, 4), 256, 0, stream>>>((const uint2*)h2s, dinv, b2, rowptr, ssrc, out);
}